// Round 1
// baseline (8759.132 us; speedup 1.0000x reference)
//
#include <hip/hip_runtime.h>
#include <hip/hip_bf16.h>
#include <math.h>

#define NN 100000
#define NE 1600000
#define HID 128
#define NG 512

// ---------------- degree histogram + dinv ----------------
__global__ __launch_bounds__(256) void deg_hist(const int* __restrict__ col, float* __restrict__ deg, int E) {
    int t = blockIdx.x * 256 + threadIdx.x;
    if (t < E) unsafeAtomicAdd(&deg[col[t]], 1.0f);
}

__global__ __launch_bounds__(256) void make_dinv(float* __restrict__ deg, int n) {
    int t = blockIdx.x * 256 + threadIdx.x;
    if (t < n) deg[t] = rsqrtf(deg[t] + 1.0f);   // +1 self-loop; always >= 1
}

// ---------------- GEMM: out[N,128] = A[N,128] @ W[128,128] (+bias, +elu) ----------------
// tile 64 rows x 64 cols, 256 threads, 4x4 register blocking
__global__ __launch_bounds__(256) void gemm128(const float* __restrict__ A,
                                               const float* __restrict__ W,
                                               const float* __restrict__ bias,
                                               float* __restrict__ out,
                                               int N, int applyElu) {
    __shared__ float xs[64][128];   // 32 KB
    __shared__ float ws[128][64];   // 32 KB
    const int tid = threadIdx.x;
    const int rowBase = blockIdx.x * 64;
    const int colBase = blockIdx.y * 64;

    // stage A tile (64x128)
#pragma unroll
    for (int it = 0; it < 8; ++it) {
        int idx = it * 256 + tid;
        int r = idx >> 5;
        int c4 = (idx & 31) << 2;
        int gr = rowBase + r;
        float4 v = make_float4(0.f, 0.f, 0.f, 0.f);
        if (gr < N) v = *(const float4*)(A + (size_t)gr * 128 + c4);
        *(float4*)(&xs[r][c4]) = v;
    }
    // stage W tile (128x64)
#pragma unroll
    for (int it = 0; it < 8; ++it) {
        int idx = it * 256 + tid;
        int k = idx >> 4;
        int c4 = (idx & 15) << 2;
        *(float4*)(&ws[k][c4]) = *(const float4*)(W + (size_t)k * 128 + colBase + c4);
    }
    __syncthreads();

    const int rowg = tid >> 4, colg = tid & 15;
    const int r0 = rowg * 4, c0 = colg * 4;
    float acc[4][4] = {};

#pragma unroll 2
    for (int kb = 0; kb < 128; kb += 4) {
        float4 xr[4], wr[4];
#pragma unroll
        for (int i = 0; i < 4; ++i) xr[i] = *(const float4*)(&xs[r0 + i][kb]);
#pragma unroll
        for (int kk = 0; kk < 4; ++kk) wr[kk] = *(const float4*)(&ws[kb + kk][c0]);
#pragma unroll
        for (int i = 0; i < 4; ++i) {
            const float* xp = (const float*)&xr[i];
#pragma unroll
            for (int kk = 0; kk < 4; ++kk) {
                float xv = xp[kk];
                acc[i][0] = fmaf(xv, wr[kk].x, acc[i][0]);
                acc[i][1] = fmaf(xv, wr[kk].y, acc[i][1]);
                acc[i][2] = fmaf(xv, wr[kk].z, acc[i][2]);
                acc[i][3] = fmaf(xv, wr[kk].w, acc[i][3]);
            }
        }
    }

    float4 b4 = make_float4(0.f, 0.f, 0.f, 0.f);
    if (bias) b4 = *(const float4*)(bias + colBase + c0);
#pragma unroll
    for (int i = 0; i < 4; ++i) {
        int gr = rowBase + r0 + i;
        if (gr < N) {
            float4 o;
            o.x = acc[i][0] + b4.x;
            o.y = acc[i][1] + b4.y;
            o.z = acc[i][2] + b4.z;
            o.w = acc[i][3] + b4.w;
            if (applyElu) {
                o.x = o.x > 0.f ? o.x : expf(o.x) - 1.f;
                o.y = o.y > 0.f ? o.y : expf(o.y) - 1.f;
                o.z = o.z > 0.f ? o.z : expf(o.z) - 1.f;
                o.w = o.w > 0.f ? o.w : expf(o.w) - 1.f;
            }
            *(float4*)(out + (size_t)gr * 128 + colBase + c0) = o;
        }
    }
}

// ---------------- edge scatter: agg[dst] += dinv[src]*dinv[dst] * hw[src] ----------------
// 32 lanes per edge, float4 per lane
__global__ __launch_bounds__(256) void scatter_edges(const int* __restrict__ rows,
                                                     const int* __restrict__ cols,
                                                     const float* __restrict__ dinv,
                                                     const float* __restrict__ hw,
                                                     float* __restrict__ agg) {
    long t = (long)blockIdx.x * 256 + threadIdx.x;
    int e = (int)(t >> 5);
    if (e >= NE) return;
    int c4 = ((int)t & 31) << 2;
    int s = rows[e], d = cols[e];
    float w = dinv[s] * dinv[d];
    const float4 v = *(const float4*)(hw + (size_t)s * 128 + c4);
    float* p = agg + (size_t)d * 128 + c4;
    unsafeAtomicAdd(p + 0, w * v.x);
    unsafeAtomicAdd(p + 1, w * v.y);
    unsafeAtomicAdd(p + 2, w * v.z);
    unsafeAtomicAdd(p + 3, w * v.w);
}

// ---------------- finish layer: h = elu(agg + dinv^2 * hw + bias) ----------------
__global__ __launch_bounds__(256) void finish_layer(float* __restrict__ h,
                                                    const float* __restrict__ hw,
                                                    const float* __restrict__ dinv,
                                                    const float* __restrict__ bias) {
    long idx = (long)blockIdx.x * 256 + threadIdx.x;   // float4 index
    if (idx >= (long)NN * 32) return;
    int v = (int)(idx >> 5);
    int c4 = ((int)idx & 31) << 2;
    float di = dinv[v];
    float w = di * di;
    float4 a = *(float4*)(h + (size_t)v * 128 + c4);
    float4 x = *(const float4*)(hw + (size_t)v * 128 + c4);
    float4 b = *(const float4*)(bias + c4);
    float4 o;
    o.x = a.x + w * x.x + b.x;
    o.y = a.y + w * x.y + b.y;
    o.z = a.z + w * x.z + b.z;
    o.w = a.w + w * x.w + b.w;
    o.x = o.x > 0.f ? o.x : expf(o.x) - 1.f;
    o.y = o.y > 0.f ? o.y : expf(o.y) - 1.f;
    o.z = o.z > 0.f ? o.z : expf(o.z) - 1.f;
    o.w = o.w > 0.f ? o.w : expf(o.w) - 1.f;
    *(float4*)(h + (size_t)v * 128 + c4) = o;
}

// ---------------- readout: reps[g] += mean over nodes of graph g ----------------
__global__ __launch_bounds__(128) void readout(const float* __restrict__ h,
                                               const int* __restrict__ batch,
                                               int n, float* __restrict__ reps) {
    int g = blockIdx.x;
    // lower_bound(batch, g) and lower_bound(batch, g+1)
    int lo = 0, hi = n;
    while (lo < hi) { int m = (lo + hi) >> 1; if (batch[m] < g) lo = m + 1; else hi = m; }
    int s = lo;
    lo = 0; hi = n;
    while (lo < hi) { int m = (lo + hi) >> 1; if (batch[m] < g + 1) lo = m + 1; else hi = m; }
    int e = lo;
    int c = threadIdx.x;
    float acc = 0.f;
    for (int v = s; v < e; ++v) acc += h[(size_t)v * 128 + c];
    float cnt = (float)(e - s > 0 ? e - s : 1);
    reps[(size_t)g * 128 + c] += acc / cnt;
}

// ---------------- classifier + log_softmax ----------------
__global__ __launch_bounds__(64) void cls_logsoftmax(const float* __restrict__ g,
                                                     const float* __restrict__ cw,
                                                     const float* __restrict__ cb,
                                                     float* __restrict__ out) {
    int r = blockIdx.x;
    __shared__ float row[128];
    __shared__ float lg[10];
    int t = threadIdx.x;
    row[t] = g[(size_t)r * 128 + t];
    row[64 + t] = g[(size_t)r * 128 + 64 + t];
    __syncthreads();
    if (t < 10) {
        float a = cb[t];
        for (int k = 0; k < 128; ++k) a = fmaf(row[k], cw[k * 10 + t], a);
        lg[t] = a;
    }
    __syncthreads();
    if (t == 0) {
        float m = lg[0];
#pragma unroll
        for (int j = 1; j < 10; ++j) m = fmaxf(m, lg[j]);
        float se = 0.f;
#pragma unroll
        for (int j = 0; j < 10; ++j) se += expf(lg[j] - m);
        float L = logf(se);
#pragma unroll
        for (int j = 0; j < 10; ++j) out[(size_t)r * 10 + j] = lg[j] - m - L;
    }
}

extern "C" void kernel_launch(void* const* d_in, const int* in_sizes, int n_in,
                              void* d_out, int out_size, void* d_ws, size_t ws_size,
                              hipStream_t stream) {
    const float* x        = (const float*)d_in[0];
    const float* lin1_w   = (const float*)d_in[1];
    const float* lin1_b   = (const float*)d_in[2];
    const float* gcn_w    = (const float*)d_in[3];
    const float* gcn_b    = (const float*)d_in[4];
    const float* lin_out_w= (const float*)d_in[5];
    const float* lin_out_b= (const float*)d_in[6];
    const float* cls_w    = (const float*)d_in[7];
    const float* cls_b    = (const float*)d_in[8];
    const int*   ei       = (const int*)d_in[9];    // [2, NE]
    const int*   batch    = (const int*)d_in[10];   // [NN]
    float* out = (float*)d_out;

    const int* erow = ei;         // source
    const int* ecol = ei + NE;    // target

    float* h    = (float*)d_ws;            // NN*128
    float* hw   = h + (size_t)NN * 128;    // NN*128
    float* dinv = hw + (size_t)NN * 128;   // NN
    float* reps = dinv + NN;               // NG*128
    float* gbuf = reps + (size_t)NG * 128; // NG*128

    // zero deg (in dinv buffer) and reps
    hipMemsetAsync(dinv, 0, NN * sizeof(float), stream);
    hipMemsetAsync(reps, 0, (size_t)NG * 128 * sizeof(float), stream);

    deg_hist<<<(NE + 255) / 256, 256, 0, stream>>>(ecol, dinv, NE);
    make_dinv<<<(NN + 255) / 256, 256, 0, stream>>>(dinv, NN);

    // h = elu(x @ lin1_w + b)
    dim3 gg((NN + 63) / 64, 2);
    gemm128<<<gg, 256, 0, stream>>>(x, lin1_w, lin1_b, h, NN, 1);
    readout<<<NG, 128, 0, stream>>>(h, batch, NN, reps);

    for (int i = 0; i < 3; ++i) {
        gemm128<<<gg, 256, 0, stream>>>(h, gcn_w + (size_t)i * 128 * 128, nullptr, hw, NN, 0);
        hipMemsetAsync(h, 0, (size_t)NN * 128 * sizeof(float), stream);
        scatter_edges<<<(int)(((long)NE * 32 + 255) / 256), 256, 0, stream>>>(erow, ecol, dinv, hw, h);
        finish_layer<<<(int)(((long)NN * 32 + 255) / 256), 256, 0, stream>>>(h, hw, dinv, gcn_b + (size_t)i * 128);
        readout<<<NG, 128, 0, stream>>>(h, batch, NN, reps);
    }

    // g = elu(reps @ lin_out_w + b)
    dim3 gs((NG + 63) / 64, 2);
    gemm128<<<gs, 256, 0, stream>>>(reps, lin_out_w, lin_out_b, gbuf, NG, 1);
    cls_logsoftmax<<<NG, 64, 0, stream>>>(gbuf, cls_w, cls_b, out);
}

// Round 2
// 1099.849 us; speedup vs baseline: 7.9639x; 7.9639x over previous
//
#include <hip/hip_runtime.h>
#include <hip/hip_bf16.h>
#include <math.h>

#define NN 100000
#define NE 1600000
#define HID 128
#define NG 512

// ---------------- in-degree histogram (int) ----------------
__global__ __launch_bounds__(256) void deg_hist(const int* __restrict__ col, int* __restrict__ cnt, int E) {
    int t = blockIdx.x * 256 + threadIdx.x;
    if (t < E) atomicAdd(&cnt[col[t]], 1);
}

__global__ __launch_bounds__(256) void make_dinv(const int* __restrict__ cnt, float* __restrict__ dinv, int n) {
    int t = blockIdx.x * 256 + threadIdx.x;
    if (t < n) dinv[t] = rsqrtf((float)cnt[t] + 1.0f);   // +1 self-loop; always >= 1
}

// ---------------- 3-step exclusive prefix scan of cnt -> row_ptr ----------------
// step 1: per-block (1024 elems) exclusive scan + block total
__global__ __launch_bounds__(256) void scan_local(const int* __restrict__ cnt, int* __restrict__ rp,
                                                  int* __restrict__ bsum, int n) {
    __shared__ int s[256];
    const int b = blockIdx.x, t = threadIdx.x;
    const int base = b * 1024 + t * 4;
    int v[4], sum = 0;
#pragma unroll
    for (int j = 0; j < 4; ++j) { int idx = base + j; v[j] = (idx < n) ? cnt[idx] : 0; sum += v[j]; }
    s[t] = sum;
    __syncthreads();
    for (int off = 1; off < 256; off <<= 1) {
        int x = (t >= off) ? s[t - off] : 0;
        __syncthreads();
        s[t] += x;
        __syncthreads();
    }
    if (t == 255) bsum[b] = s[255];
    int run = (t > 0) ? s[t - 1] : 0;
#pragma unroll
    for (int j = 0; j < 4; ++j) { int idx = base + j; if (idx < n) rp[idx] = run; run += v[j]; }
}

// step 2: scan the ~98 block totals (single thread; trivial)
__global__ void scan_blocks(int* __restrict__ bsum, int nb) {
    if (threadIdx.x == 0 && blockIdx.x == 0) {
        int run = 0;
        for (int i = 0; i < nb; ++i) { int x = bsum[i]; bsum[i] = run; run += x; }
        bsum[nb] = run;
    }
}

// step 3: add block offsets; set rp[n] = total
__global__ __launch_bounds__(256) void scan_add(int* __restrict__ rp, const int* __restrict__ bsum, int n, int nb) {
    int i = blockIdx.x * 256 + threadIdx.x;
    if (i < n) rp[i] += bsum[i >> 10];
    if (i == 0) rp[n] = bsum[nb];
}

// ---------------- fill CSR: csrc[slot] = src, grouped by dst ----------------
__global__ __launch_bounds__(256) void fill_csr(const int* __restrict__ row, const int* __restrict__ col,
                                                const int* __restrict__ rp, int* __restrict__ cur,
                                                int* __restrict__ csrc, int E) {
    int e = blockIdx.x * 256 + threadIdx.x;
    if (e < E) {
        int d = col[e];
        int slot = atomicAdd(&cur[d], 1);
        csrc[rp[d] + slot] = row[e];
    }
}

// ---------------- GEMM: out[N,128] = A[N,128] @ W[128,128] (+bias, +elu) ----------------
__global__ __launch_bounds__(256) void gemm128(const float* __restrict__ A,
                                               const float* __restrict__ W,
                                               const float* __restrict__ bias,
                                               float* __restrict__ out,
                                               int N, int applyElu) {
    __shared__ float xs[64][128];   // 32 KB
    __shared__ float ws[128][64];   // 32 KB
    const int tid = threadIdx.x;
    const int rowBase = blockIdx.x * 64;
    const int colBase = blockIdx.y * 64;

#pragma unroll
    for (int it = 0; it < 8; ++it) {
        int idx = it * 256 + tid;
        int r = idx >> 5;
        int c4 = (idx & 31) << 2;
        int gr = rowBase + r;
        float4 v = make_float4(0.f, 0.f, 0.f, 0.f);
        if (gr < N) v = *(const float4*)(A + (size_t)gr * 128 + c4);
        *(float4*)(&xs[r][c4]) = v;
    }
#pragma unroll
    for (int it = 0; it < 8; ++it) {
        int idx = it * 256 + tid;
        int k = idx >> 4;
        int c4 = (idx & 15) << 2;
        *(float4*)(&ws[k][c4]) = *(const float4*)(W + (size_t)k * 128 + colBase + c4);
    }
    __syncthreads();

    const int rowg = tid >> 4, colg = tid & 15;
    const int r0 = rowg * 4, c0 = colg * 4;
    float acc[4][4] = {};

#pragma unroll 2
    for (int kb = 0; kb < 128; kb += 4) {
        float4 xr[4], wr[4];
#pragma unroll
        for (int i = 0; i < 4; ++i) xr[i] = *(const float4*)(&xs[r0 + i][kb]);
#pragma unroll
        for (int kk = 0; kk < 4; ++kk) wr[kk] = *(const float4*)(&ws[kb + kk][c0]);
#pragma unroll
        for (int i = 0; i < 4; ++i) {
            const float* xp = (const float*)&xr[i];
#pragma unroll
            for (int kk = 0; kk < 4; ++kk) {
                float xv = xp[kk];
                acc[i][0] = fmaf(xv, wr[kk].x, acc[i][0]);
                acc[i][1] = fmaf(xv, wr[kk].y, acc[i][1]);
                acc[i][2] = fmaf(xv, wr[kk].z, acc[i][2]);
                acc[i][3] = fmaf(xv, wr[kk].w, acc[i][3]);
            }
        }
    }

    float4 b4 = make_float4(0.f, 0.f, 0.f, 0.f);
    if (bias) b4 = *(const float4*)(bias + colBase + c0);
#pragma unroll
    for (int i = 0; i < 4; ++i) {
        int gr = rowBase + r0 + i;
        if (gr < N) {
            float4 o;
            o.x = acc[i][0] + b4.x;
            o.y = acc[i][1] + b4.y;
            o.z = acc[i][2] + b4.z;
            o.w = acc[i][3] + b4.w;
            if (applyElu) {
                o.x = o.x > 0.f ? o.x : expf(o.x) - 1.f;
                o.y = o.y > 0.f ? o.y : expf(o.y) - 1.f;
                o.z = o.z > 0.f ? o.z : expf(o.z) - 1.f;
                o.w = o.w > 0.f ? o.w : expf(o.w) - 1.f;
            }
            *(float4*)(out + (size_t)gr * 128 + colBase + c0) = o;
        }
    }
}

// ---------------- gather-aggregate + self-loop + bias + ELU ----------------
// 32 lanes per node (float4 per lane), 8 nodes per 256-thread block
__global__ __launch_bounds__(256) void gather_agg(const int* __restrict__ rp,
                                                  const int* __restrict__ csrc,
                                                  const float* __restrict__ dinv,
                                                  const float* __restrict__ hw,
                                                  const float* __restrict__ bias,
                                                  float* __restrict__ h) {
    int v = blockIdx.x * 8 + (threadIdx.x >> 5);
    if (v >= NN) return;
    int c4 = (threadIdx.x & 31) << 2;
    float di = dinv[v];
    int s = rp[v], e = rp[v + 1];
    float4 acc = make_float4(0.f, 0.f, 0.f, 0.f);
    for (int i = s; i < e; ++i) {
        int u = csrc[i];
        float w = dinv[u] * di;
        const float4 t = *(const float4*)(hw + (size_t)u * 128 + c4);
        acc.x = fmaf(w, t.x, acc.x);
        acc.y = fmaf(w, t.y, acc.y);
        acc.z = fmaf(w, t.z, acc.z);
        acc.w = fmaf(w, t.w, acc.w);
    }
    // self-loop + bias + ELU
    const float4 sv = *(const float4*)(hw + (size_t)v * 128 + c4);
    const float4 b  = *(const float4*)(bias + c4);
    float w2 = di * di;
    float4 o;
    o.x = acc.x + w2 * sv.x + b.x;
    o.y = acc.y + w2 * sv.y + b.y;
    o.z = acc.z + w2 * sv.z + b.z;
    o.w = acc.w + w2 * sv.w + b.w;
    o.x = o.x > 0.f ? o.x : expf(o.x) - 1.f;
    o.y = o.y > 0.f ? o.y : expf(o.y) - 1.f;
    o.z = o.z > 0.f ? o.z : expf(o.z) - 1.f;
    o.w = o.w > 0.f ? o.w : expf(o.w) - 1.f;
    *(float4*)(h + (size_t)v * 128 + c4) = o;
}

// ---------------- readout: reps[g] += mean over nodes of graph g ----------------
__global__ __launch_bounds__(128) void readout(const float* __restrict__ h,
                                               const int* __restrict__ batch,
                                               int n, float* __restrict__ reps) {
    int g = blockIdx.x;
    int lo = 0, hi = n;
    while (lo < hi) { int m = (lo + hi) >> 1; if (batch[m] < g) lo = m + 1; else hi = m; }
    int s = lo;
    lo = 0; hi = n;
    while (lo < hi) { int m = (lo + hi) >> 1; if (batch[m] < g + 1) lo = m + 1; else hi = m; }
    int e = lo;
    int c = threadIdx.x;
    float acc = 0.f;
    for (int v = s; v < e; ++v) acc += h[(size_t)v * 128 + c];
    float cnt = (float)(e - s > 0 ? e - s : 1);
    reps[(size_t)g * 128 + c] += acc / cnt;
}

// ---------------- classifier + log_softmax ----------------
__global__ __launch_bounds__(64) void cls_logsoftmax(const float* __restrict__ g,
                                                     const float* __restrict__ cw,
                                                     const float* __restrict__ cb,
                                                     float* __restrict__ out) {
    int r = blockIdx.x;
    __shared__ float row[128];
    __shared__ float lg[10];
    int t = threadIdx.x;
    row[t] = g[(size_t)r * 128 + t];
    row[64 + t] = g[(size_t)r * 128 + 64 + t];
    __syncthreads();
    if (t < 10) {
        float a = cb[t];
        for (int k = 0; k < 128; ++k) a = fmaf(row[k], cw[k * 10 + t], a);
        lg[t] = a;
    }
    __syncthreads();
    if (t == 0) {
        float m = lg[0];
#pragma unroll
        for (int j = 1; j < 10; ++j) m = fmaxf(m, lg[j]);
        float se = 0.f;
#pragma unroll
        for (int j = 0; j < 10; ++j) se += expf(lg[j] - m);
        float L = logf(se);
#pragma unroll
        for (int j = 0; j < 10; ++j) out[(size_t)r * 10 + j] = lg[j] - m - L;
    }
}

extern "C" void kernel_launch(void* const* d_in, const int* in_sizes, int n_in,
                              void* d_out, int out_size, void* d_ws, size_t ws_size,
                              hipStream_t stream) {
    const float* x        = (const float*)d_in[0];
    const float* lin1_w   = (const float*)d_in[1];
    const float* lin1_b   = (const float*)d_in[2];
    const float* gcn_w    = (const float*)d_in[3];
    const float* gcn_b    = (const float*)d_in[4];
    const float* lin_out_w= (const float*)d_in[5];
    const float* lin_out_b= (const float*)d_in[6];
    const float* cls_w    = (const float*)d_in[7];
    const float* cls_b    = (const float*)d_in[8];
    const int*   ei       = (const int*)d_in[9];    // [2, NE]
    const int*   batch    = (const int*)d_in[10];   // [NN]
    float* out = (float*)d_out;

    const int* erow = ei;         // source
    const int* ecol = ei + NE;    // target

    const int NB_SCAN = (NN + 1023) / 1024;  // 98

    float* h    = (float*)d_ws;                    // NN*128
    float* hw   = h + (size_t)NN * 128;            // NN*128
    float* dinv = hw + (size_t)NN * 128;           // NN
    float* reps = dinv + NN;                       // NG*128
    float* gbuf = reps + (size_t)NG * 128;         // NG*128
    int*   cnt  = (int*)(gbuf + (size_t)NG * 128); // NN
    int*   rp   = cnt + NN;                        // NN+1
    int*   cur  = rp + NN + 1;                     // NN
    int*   bsum = cur + NN;                        // NB_SCAN+1
    int*   csrc = bsum + NB_SCAN + 1;              // NE

    hipMemsetAsync(cnt, 0, NN * sizeof(int), stream);
    hipMemsetAsync(cur, 0, NN * sizeof(int), stream);
    hipMemsetAsync(reps, 0, (size_t)NG * 128 * sizeof(float), stream);

    // ---- CSR build ----
    deg_hist<<<(NE + 255) / 256, 256, 0, stream>>>(ecol, cnt, NE);
    make_dinv<<<(NN + 255) / 256, 256, 0, stream>>>(cnt, dinv, NN);
    scan_local<<<NB_SCAN, 256, 0, stream>>>(cnt, rp, bsum, NN);
    scan_blocks<<<1, 64, 0, stream>>>(bsum, NB_SCAN);
    scan_add<<<(NN + 255) / 256, 256, 0, stream>>>(rp, bsum, NN, NB_SCAN);
    fill_csr<<<(NE + 255) / 256, 256, 0, stream>>>(erow, ecol, rp, cur, csrc, NE);

    // ---- h = elu(x @ lin1_w + b) ----
    dim3 gg((NN + 63) / 64, 2);
    gemm128<<<gg, 256, 0, stream>>>(x, lin1_w, lin1_b, h, NN, 1);
    readout<<<NG, 128, 0, stream>>>(h, batch, NN, reps);

    for (int i = 0; i < 3; ++i) {
        gemm128<<<gg, 256, 0, stream>>>(h, gcn_w + (size_t)i * 128 * 128, nullptr, hw, NN, 0);
        gather_agg<<<(NN + 7) / 8, 256, 0, stream>>>(rp, csrc, dinv, hw, gcn_b + (size_t)i * 128, h);
        readout<<<NG, 128, 0, stream>>>(h, batch, NN, reps);
    }

    // ---- head ----
    dim3 gs((NG + 63) / 64, 2);
    gemm128<<<gs, 256, 0, stream>>>(reps, lin_out_w, lin_out_b, gbuf, NG, 1);
    cls_logsoftmax<<<NG, 64, 0, stream>>>(gbuf, cls_w, cls_b, out);
}

// Round 3
// 954.078 us; speedup vs baseline: 9.1807x; 1.1528x over previous
//
#include <hip/hip_runtime.h>
#include <hip/hip_bf16.h>
#include <math.h>

#define NN 100000
#define NE 1600000
#define HID 128
#define NG 512

typedef unsigned short ushort_t;
typedef __attribute__((ext_vector_type(8))) short bf16x8;
typedef __attribute__((ext_vector_type(4))) float f32x4;

// ---- bf16 helpers (manual RNE; avoids __hip_bfloat16 ABI differences) ----
__device__ __forceinline__ ushort_t f2bf(float v) {
    unsigned u = __float_as_uint(v);
    unsigned r = (u + 0x7FFF + ((u >> 16) & 1)) >> 16;
    return (ushort_t)r;
}
__device__ __forceinline__ float bf2f(ushort_t u) {
    return __uint_as_float((unsigned)u << 16);
}

// ---------------- in-degree histogram (int) ----------------
__global__ __launch_bounds__(256) void deg_hist(const int* __restrict__ col, int* __restrict__ cnt, int E) {
    int t = blockIdx.x * 256 + threadIdx.x;
    if (t < E) atomicAdd(&cnt[col[t]], 1);
}

__global__ __launch_bounds__(256) void make_dinv(const int* __restrict__ cnt, float* __restrict__ dinv, int n) {
    int t = blockIdx.x * 256 + threadIdx.x;
    if (t < n) dinv[t] = rsqrtf((float)cnt[t] + 1.0f);
}

// ---------------- 3-step exclusive prefix scan ----------------
__global__ __launch_bounds__(256) void scan_local(const int* __restrict__ cnt, int* __restrict__ rp,
                                                  int* __restrict__ bsum, int n) {
    __shared__ int s[256];
    const int b = blockIdx.x, t = threadIdx.x;
    const int base = b * 1024 + t * 4;
    int v[4], sum = 0;
#pragma unroll
    for (int j = 0; j < 4; ++j) { int idx = base + j; v[j] = (idx < n) ? cnt[idx] : 0; sum += v[j]; }
    s[t] = sum;
    __syncthreads();
    for (int off = 1; off < 256; off <<= 1) {
        int x = (t >= off) ? s[t - off] : 0;
        __syncthreads();
        s[t] += x;
        __syncthreads();
    }
    if (t == 255) bsum[b] = s[255];
    int run = (t > 0) ? s[t - 1] : 0;
#pragma unroll
    for (int j = 0; j < 4; ++j) { int idx = base + j; if (idx < n) rp[idx] = run; run += v[j]; }
}

__global__ void scan_blocks(int* __restrict__ bsum, int nb) {
    if (threadIdx.x == 0 && blockIdx.x == 0) {
        int run = 0;
        for (int i = 0; i < nb; ++i) { int x = bsum[i]; bsum[i] = run; run += x; }
        bsum[nb] = run;
    }
}

__global__ __launch_bounds__(256) void scan_add(int* __restrict__ rp, const int* __restrict__ bsum, int n, int nb) {
    int i = blockIdx.x * 256 + threadIdx.x;
    if (i < n) rp[i] += bsum[i >> 10];
    if (i == 0) rp[n] = bsum[nb];
}

// ---------------- fill CSR ----------------
__global__ __launch_bounds__(256) void fill_csr(const int* __restrict__ row, const int* __restrict__ col,
                                                const int* __restrict__ rp, int* __restrict__ cur,
                                                int* __restrict__ csrc, int E) {
    int e = blockIdx.x * 256 + threadIdx.x;
    if (e < E) {
        int d = col[e];
        int slot = atomicAdd(&cur[d], 1);
        csrc[rp[d] + slot] = row[e];
    }
}

// ---------------- weight prep: transpose + bf16 hi/lo split ----------------
// Wt_hi/Wt_lo[m][n][k], m = 0 (lin1) or 1..3 (gcn layers)
__global__ __launch_bounds__(256) void prep_w(const float* __restrict__ lin1_w,
                                              const float* __restrict__ gcn_w,
                                              ushort_t* __restrict__ wt_hi,
                                              ushort_t* __restrict__ wt_lo) {
    int m = blockIdx.x;
    const float* W = (m == 0) ? lin1_w : gcn_w + (size_t)(m - 1) * 16384;
    ushort_t* hi = wt_hi + (size_t)m * 16384;
    ushort_t* lo = wt_lo + (size_t)m * 16384;
    for (int i = threadIdx.x; i < 16384; i += 256) {
        int k = i >> 7, n = i & 127;
        float v = W[i];                 // W[k][n]
        ushort_t h = f2bf(v);
        ushort_t l = f2bf(v - bf2f(h));
        hi[n * 128 + k] = h;            // transposed [n][k]
        lo[n * 128 + k] = l;
    }
}

// ---------------- MFMA GEMM: out[N,128] = A[N,128] @ W, 3-term bf16 split ----------------
// block = 256 thr = 4 waves; wave covers 32 rows x 128 cols; no LDS.
// mode 0: out_f32 = elu(acc + bias);  mode 1: out_bf16 = bf16(acc)
__global__ __launch_bounds__(256) void gemm_mfma(const float* __restrict__ A,
                                                 const ushort_t* __restrict__ wt_hi,
                                                 const ushort_t* __restrict__ wt_lo,
                                                 const float* __restrict__ bias,
                                                 float* __restrict__ out_f32,
                                                 ushort_t* __restrict__ out_bf16,
                                                 int N, int mode) {
    const int lane = threadIdx.x & 63;
    const int wid = threadIdx.x >> 6;
    const int rowBase = blockIdx.x * 128 + wid * 32;
    const int l15 = lane & 15, lg = lane >> 4;

    f32x4 acc[2][8];
#pragma unroll
    for (int rt = 0; rt < 2; ++rt)
#pragma unroll
        for (int ct = 0; ct < 8; ++ct) acc[rt][ct] = (f32x4){0.f, 0.f, 0.f, 0.f};

#pragma unroll
    for (int ks = 0; ks < 4; ++ks) {
        bf16x8 ahi[2], alo[2];
#pragma unroll
        for (int rt = 0; rt < 2; ++rt) {
            int r = rowBase + rt * 16 + l15;
            float av[8];
            if (r < N) {
                const float* ap = A + (size_t)r * 128 + ks * 32 + lg * 8;
                float4 a0 = *(const float4*)(ap);
                float4 a1 = *(const float4*)(ap + 4);
                av[0] = a0.x; av[1] = a0.y; av[2] = a0.z; av[3] = a0.w;
                av[4] = a1.x; av[5] = a1.y; av[6] = a1.z; av[7] = a1.w;
            } else {
#pragma unroll
                for (int j = 0; j < 8; ++j) av[j] = 0.f;
            }
#pragma unroll
            for (int j = 0; j < 8; ++j) {
                ushort_t h = f2bf(av[j]);
                ahi[rt][j] = (short)h;
                alo[rt][j] = (short)f2bf(av[j] - bf2f(h));
            }
        }
#pragma unroll
        for (int ct = 0; ct < 8; ++ct) {
            size_t boff = (size_t)(ct * 16 + l15) * 128 + ks * 32 + lg * 8;
            bf16x8 bhi = *(const bf16x8*)(wt_hi + boff);
            bf16x8 blo = *(const bf16x8*)(wt_lo + boff);
            acc[0][ct] = __builtin_amdgcn_mfma_f32_16x16x32_bf16(ahi[0], bhi, acc[0][ct], 0, 0, 0);
            acc[1][ct] = __builtin_amdgcn_mfma_f32_16x16x32_bf16(ahi[1], bhi, acc[1][ct], 0, 0, 0);
            acc[0][ct] = __builtin_amdgcn_mfma_f32_16x16x32_bf16(alo[0], bhi, acc[0][ct], 0, 0, 0);
            acc[1][ct] = __builtin_amdgcn_mfma_f32_16x16x32_bf16(alo[1], bhi, acc[1][ct], 0, 0, 0);
            acc[0][ct] = __builtin_amdgcn_mfma_f32_16x16x32_bf16(ahi[0], blo, acc[0][ct], 0, 0, 0);
            acc[1][ct] = __builtin_amdgcn_mfma_f32_16x16x32_bf16(ahi[1], blo, acc[1][ct], 0, 0, 0);
        }
    }

    // epilogue; C/D: col = lane&15, row_local = (lane>>4)*4 + reg
#pragma unroll
    for (int rt = 0; rt < 2; ++rt) {
#pragma unroll
        for (int reg = 0; reg < 4; ++reg) {
            int row = rowBase + rt * 16 + lg * 4 + reg;
            if (row >= N) continue;
#pragma unroll
            for (int ct = 0; ct < 8; ++ct) {
                int colc = ct * 16 + l15;
                float v = acc[rt][ct][reg];
                if (mode == 0) {
                    v += bias[colc];
                    v = v > 0.f ? v : expf(v) - 1.f;
                    out_f32[(size_t)row * 128 + colc] = v;
                } else {
                    out_bf16[(size_t)row * 128 + colc] = f2bf(v);
                }
            }
        }
    }
}

// ---------------- gather-aggregate (bf16 msgs) + self-loop + bias + ELU ----------------
// 32 lanes per node (4 bf16 per lane), 8 nodes per 256-thread block
__global__ __launch_bounds__(256) void gather_agg(const int* __restrict__ rp,
                                                  const int* __restrict__ csrc,
                                                  const float* __restrict__ dinv,
                                                  const ushort_t* __restrict__ hwb,
                                                  const float* __restrict__ bias,
                                                  float* __restrict__ h) {
    int v = blockIdx.x * 8 + (threadIdx.x >> 5);
    if (v >= NN) return;
    int c4 = (threadIdx.x & 31) << 2;
    float di = dinv[v];
    int s = rp[v], e = rp[v + 1];
    float4 acc = make_float4(0.f, 0.f, 0.f, 0.f);
    for (int i = s; i < e; ++i) {
        int u = csrc[i];
        float w = dinv[u] * di;
        ushort4 t = *(const ushort4*)(hwb + (size_t)u * 128 + c4);
        acc.x = fmaf(w, bf2f(t.x), acc.x);
        acc.y = fmaf(w, bf2f(t.y), acc.y);
        acc.z = fmaf(w, bf2f(t.z), acc.z);
        acc.w = fmaf(w, bf2f(t.w), acc.w);
    }
    ushort4 sv = *(const ushort4*)(hwb + (size_t)v * 128 + c4);
    const float4 b = *(const float4*)(bias + c4);
    float w2 = di * di;
    float4 o;
    o.x = acc.x + w2 * bf2f(sv.x) + b.x;
    o.y = acc.y + w2 * bf2f(sv.y) + b.y;
    o.z = acc.z + w2 * bf2f(sv.z) + b.z;
    o.w = acc.w + w2 * bf2f(sv.w) + b.w;
    o.x = o.x > 0.f ? o.x : expf(o.x) - 1.f;
    o.y = o.y > 0.f ? o.y : expf(o.y) - 1.f;
    o.z = o.z > 0.f ? o.z : expf(o.z) - 1.f;
    o.w = o.w > 0.f ? o.w : expf(o.w) - 1.f;
    *(float4*)(h + (size_t)v * 128 + c4) = o;
}

// ---------------- readout: reps[g] += mean over nodes of graph g ----------------
__global__ __launch_bounds__(128) void readout(const float* __restrict__ h,
                                               const int* __restrict__ batch,
                                               int n, float* __restrict__ reps) {
    int g = blockIdx.x;
    int lo = 0, hi = n;
    while (lo < hi) { int m = (lo + hi) >> 1; if (batch[m] < g) lo = m + 1; else hi = m; }
    int s = lo;
    lo = 0; hi = n;
    while (lo < hi) { int m = (lo + hi) >> 1; if (batch[m] < g + 1) lo = m + 1; else hi = m; }
    int e = lo;
    __shared__ float part[4][128];
    int rid = threadIdx.x >> 5;
    int c4 = (threadIdx.x & 31) << 2;
    float4 acc = make_float4(0.f, 0.f, 0.f, 0.f);
    for (int v = s + rid; v < e; v += 4) {
        float4 t = *(const float4*)(h + (size_t)v * 128 + c4);
        acc.x += t.x; acc.y += t.y; acc.z += t.z; acc.w += t.w;
    }
    *(float4*)(&part[rid][c4]) = acc;
    __syncthreads();
    if (rid == 0) {
        float4 a0 = *(const float4*)(&part[0][c4]);
        float4 a1 = *(const float4*)(&part[1][c4]);
        float4 a2 = *(const float4*)(&part[2][c4]);
        float4 a3 = *(const float4*)(&part[3][c4]);
        float cnt = (float)(e - s > 0 ? e - s : 1);
        float inv = 1.f / cnt;
        float* rp_ = reps + (size_t)g * 128 + c4;
        rp_[0] += (a0.x + a1.x + a2.x + a3.x) * inv;
        rp_[1] += (a0.y + a1.y + a2.y + a3.y) * inv;
        rp_[2] += (a0.z + a1.z + a2.z + a3.z) * inv;
        rp_[3] += (a0.w + a1.w + a2.w + a3.w) * inv;
    }
}

// ---------------- head GEMM (fp32 VALU, tiny) ----------------
__global__ __launch_bounds__(256) void gemm128(const float* __restrict__ A,
                                               const float* __restrict__ W,
                                               const float* __restrict__ bias,
                                               float* __restrict__ out,
                                               int N, int applyElu) {
    __shared__ float xs[64][128];
    __shared__ float ws[128][64];
    const int tid = threadIdx.x;
    const int rowBase = blockIdx.x * 64;
    const int colBase = blockIdx.y * 64;
#pragma unroll
    for (int it = 0; it < 8; ++it) {
        int idx = it * 256 + tid;
        int r = idx >> 5;
        int c4 = (idx & 31) << 2;
        int gr = rowBase + r;
        float4 v = make_float4(0.f, 0.f, 0.f, 0.f);
        if (gr < N) v = *(const float4*)(A + (size_t)gr * 128 + c4);
        *(float4*)(&xs[r][c4]) = v;
    }
#pragma unroll
    for (int it = 0; it < 8; ++it) {
        int idx = it * 256 + tid;
        int k = idx >> 4;
        int c4 = (idx & 15) << 2;
        *(float4*)(&ws[k][c4]) = *(const float4*)(W + (size_t)k * 128 + colBase + c4);
    }
    __syncthreads();
    const int rowg = tid >> 4, colg = tid & 15;
    const int r0 = rowg * 4, c0 = colg * 4;
    float acc[4][4] = {};
#pragma unroll 2
    for (int kb = 0; kb < 128; kb += 4) {
        float4 xr[4], wr[4];
#pragma unroll
        for (int i = 0; i < 4; ++i) xr[i] = *(const float4*)(&xs[r0 + i][kb]);
#pragma unroll
        for (int kk = 0; kk < 4; ++kk) wr[kk] = *(const float4*)(&ws[kb + kk][c0]);
#pragma unroll
        for (int i = 0; i < 4; ++i) {
            const float* xp = (const float*)&xr[i];
#pragma unroll
            for (int kk = 0; kk < 4; ++kk) {
                float xv = xp[kk];
                acc[i][0] = fmaf(xv, wr[kk].x, acc[i][0]);
                acc[i][1] = fmaf(xv, wr[kk].y, acc[i][1]);
                acc[i][2] = fmaf(xv, wr[kk].z, acc[i][2]);
                acc[i][3] = fmaf(xv, wr[kk].w, acc[i][3]);
            }
        }
    }
    float4 b4 = make_float4(0.f, 0.f, 0.f, 0.f);
    if (bias) b4 = *(const float4*)(bias + colBase + c0);
#pragma unroll
    for (int i = 0; i < 4; ++i) {
        int gr = rowBase + r0 + i;
        if (gr < N) {
            float4 o;
            o.x = acc[i][0] + b4.x;
            o.y = acc[i][1] + b4.y;
            o.z = acc[i][2] + b4.z;
            o.w = acc[i][3] + b4.w;
            if (applyElu) {
                o.x = o.x > 0.f ? o.x : expf(o.x) - 1.f;
                o.y = o.y > 0.f ? o.y : expf(o.y) - 1.f;
                o.z = o.z > 0.f ? o.z : expf(o.z) - 1.f;
                o.w = o.w > 0.f ? o.w : expf(o.w) - 1.f;
            }
            *(float4*)(out + (size_t)gr * 128 + colBase + c0) = o;
        }
    }
}

// ---------------- classifier + log_softmax ----------------
__global__ __launch_bounds__(64) void cls_logsoftmax(const float* __restrict__ g,
                                                     const float* __restrict__ cw,
                                                     const float* __restrict__ cb,
                                                     float* __restrict__ out) {
    int r = blockIdx.x;
    __shared__ float row[128];
    __shared__ float lg[10];
    int t = threadIdx.x;
    row[t] = g[(size_t)r * 128 + t];
    row[64 + t] = g[(size_t)r * 128 + 64 + t];
    __syncthreads();
    if (t < 10) {
        float a = cb[t];
        for (int k = 0; k < 128; ++k) a = fmaf(row[k], cw[k * 10 + t], a);
        lg[t] = a;
    }
    __syncthreads();
    if (t == 0) {
        float m = lg[0];
#pragma unroll
        for (int j = 1; j < 10; ++j) m = fmaxf(m, lg[j]);
        float se = 0.f;
#pragma unroll
        for (int j = 0; j < 10; ++j) se += expf(lg[j] - m);
        float L = logf(se);
#pragma unroll
        for (int j = 0; j < 10; ++j) out[(size_t)r * 10 + j] = lg[j] - m - L;
    }
}

extern "C" void kernel_launch(void* const* d_in, const int* in_sizes, int n_in,
                              void* d_out, int out_size, void* d_ws, size_t ws_size,
                              hipStream_t stream) {
    const float* x        = (const float*)d_in[0];
    const float* lin1_w   = (const float*)d_in[1];
    const float* lin1_b   = (const float*)d_in[2];
    const float* gcn_w    = (const float*)d_in[3];
    const float* gcn_b    = (const float*)d_in[4];
    const float* lin_out_w= (const float*)d_in[5];
    const float* lin_out_b= (const float*)d_in[6];
    const float* cls_w    = (const float*)d_in[7];
    const float* cls_b    = (const float*)d_in[8];
    const int*   ei       = (const int*)d_in[9];
    const int*   batch    = (const int*)d_in[10];
    float* out = (float*)d_out;

    const int* erow = ei;
    const int* ecol = ei + NE;
    const int NB_SCAN = (NN + 1023) / 1024;

    float*    h     = (float*)d_ws;                        // NN*128 f32
    ushort_t* hwb   = (ushort_t*)(h + (size_t)NN * 128);   // NN*128 bf16
    float*    dinv  = (float*)(hwb + (size_t)NN * 128);    // NN
    float*    reps  = dinv + NN;                           // NG*128
    float*    gbuf  = reps + (size_t)NG * 128;             // NG*128
    int*      cnt   = (int*)(gbuf + (size_t)NG * 128);     // NN
    int*      rp    = cnt + NN;                            // NN+1
    int*      cur   = rp + NN + 1;                         // NN
    int*      bsum  = cur + NN;                            // NB_SCAN+1
    int*      csrc  = bsum + NB_SCAN + 1;                  // NE
    ushort_t* wt_hi = (ushort_t*)(csrc + NE);              // 4*16384
    ushort_t* wt_lo = wt_hi + 4 * 16384;                   // 4*16384

    hipMemsetAsync(cnt, 0, NN * sizeof(int), stream);
    hipMemsetAsync(cur, 0, NN * sizeof(int), stream);
    hipMemsetAsync(reps, 0, (size_t)NG * 128 * sizeof(float), stream);

    // CSR build + weight prep
    deg_hist<<<(NE + 255) / 256, 256, 0, stream>>>(ecol, cnt, NE);
    make_dinv<<<(NN + 255) / 256, 256, 0, stream>>>(cnt, dinv, NN);
    scan_local<<<NB_SCAN, 256, 0, stream>>>(cnt, rp, bsum, NN);
    scan_blocks<<<1, 64, 0, stream>>>(bsum, NB_SCAN);
    scan_add<<<(NN + 255) / 256, 256, 0, stream>>>(rp, bsum, NN, NB_SCAN);
    fill_csr<<<(NE + 255) / 256, 256, 0, stream>>>(erow, ecol, rp, cur, csrc, NE);
    prep_w<<<4, 256, 0, stream>>>(lin1_w, gcn_w, wt_hi, wt_lo);

    const int GEMM_GRID = (NN + 127) / 128;  // 782

    // h = elu(x @ lin1_w + b)
    gemm_mfma<<<GEMM_GRID, 256, 0, stream>>>(x, wt_hi, wt_lo, lin1_b, h, nullptr, NN, 0);
    readout<<<NG, 128, 0, stream>>>(h, batch, NN, reps);

    for (int i = 0; i < 3; ++i) {
        gemm_mfma<<<GEMM_GRID, 256, 0, stream>>>(h, wt_hi + (size_t)(i + 1) * 16384,
                                                 wt_lo + (size_t)(i + 1) * 16384,
                                                 nullptr, nullptr, hwb, NN, 1);
        gather_agg<<<(NN + 7) / 8, 256, 0, stream>>>(rp, csrc, dinv, hwb, gcn_b + (size_t)i * 128, h);
        readout<<<NG, 128, 0, stream>>>(h, batch, NN, reps);
    }

    // head
    dim3 gs((NG + 63) / 64, 2);
    gemm128<<<gs, 256, 0, stream>>>(reps, lin_out_w, lin_out_b, gbuf, NG, 1);
    cls_logsoftmax<<<NG, 64, 0, stream>>>(gbuf, cls_w, cls_b, out);
}

// Round 4
// 700.234 us; speedup vs baseline: 12.5089x; 1.3625x over previous
//
#include <hip/hip_runtime.h>
#include <hip/hip_bf16.h>
#include <math.h>

#define NN 100000
#define NE 1600000
#define HID 128
#define NG 512

typedef unsigned short ushort_t;
typedef __attribute__((ext_vector_type(8))) short bf16x8;
typedef __attribute__((ext_vector_type(8))) unsigned short ushort8_t;
typedef __attribute__((ext_vector_type(4))) float f32x4;

// ---- bf16 helpers (manual RNE) ----
__device__ __forceinline__ ushort_t f2bf(float v) {
    unsigned u = __float_as_uint(v);
    unsigned r = (u + 0x7FFF + ((u >> 16) & 1)) >> 16;
    return (ushort_t)r;
}
__device__ __forceinline__ float bf2f(ushort_t u) {
    return __uint_as_float((unsigned)u << 16);
}

// ---------------- in-degree histogram (int) ----------------
__global__ __launch_bounds__(256) void deg_hist(const int* __restrict__ col, int* __restrict__ cnt, int E) {
    int t = blockIdx.x * 256 + threadIdx.x;
    if (t < E) atomicAdd(&cnt[col[t]], 1);
}

__global__ __launch_bounds__(256) void make_dinv(const int* __restrict__ cnt, float* __restrict__ dinv, int n) {
    int t = blockIdx.x * 256 + threadIdx.x;
    if (t < n) dinv[t] = rsqrtf((float)cnt[t] + 1.0f);
}

// ---------------- 3-step exclusive prefix scan ----------------
__global__ __launch_bounds__(256) void scan_local(const int* __restrict__ cnt, int* __restrict__ rp,
                                                  int* __restrict__ bsum, int n) {
    __shared__ int s[256];
    const int b = blockIdx.x, t = threadIdx.x;
    const int base = b * 1024 + t * 4;
    int v[4], sum = 0;
#pragma unroll
    for (int j = 0; j < 4; ++j) { int idx = base + j; v[j] = (idx < n) ? cnt[idx] : 0; sum += v[j]; }
    s[t] = sum;
    __syncthreads();
    for (int off = 1; off < 256; off <<= 1) {
        int x = (t >= off) ? s[t - off] : 0;
        __syncthreads();
        s[t] += x;
        __syncthreads();
    }
    if (t == 255) bsum[b] = s[255];
    int run = (t > 0) ? s[t - 1] : 0;
#pragma unroll
    for (int j = 0; j < 4; ++j) { int idx = base + j; if (idx < n) rp[idx] = run; run += v[j]; }
}

// parallel scan of block totals (nb <= 128)
__global__ __launch_bounds__(128) void scan_blocks(int* __restrict__ bsum, int nb) {
    __shared__ int s[128];
    int t = threadIdx.x;
    int v = (t < nb) ? bsum[t] : 0;
    s[t] = v;
    __syncthreads();
    for (int off = 1; off < 128; off <<= 1) {
        int x = (t >= off) ? s[t - off] : 0;
        __syncthreads();
        s[t] += x;
        __syncthreads();
    }
    if (t < nb) bsum[t] = s[t] - v;      // exclusive
    if (t == 127) bsum[nb] = s[127];     // total
}

__global__ __launch_bounds__(256) void scan_add(int* __restrict__ rp, const int* __restrict__ bsum, int n, int nb) {
    int i = blockIdx.x * 256 + threadIdx.x;
    if (i < n) rp[i] += bsum[i >> 10];
    if (i == 0) rp[n] = bsum[nb];
}

// ---------------- fill CSR ----------------
__global__ __launch_bounds__(256) void fill_csr(const int* __restrict__ row, const int* __restrict__ col,
                                                const int* __restrict__ rp, int* __restrict__ cur,
                                                int* __restrict__ csrc, int E) {
    int e = blockIdx.x * 256 + threadIdx.x;
    if (e < E) {
        int d = col[e];
        int slot = atomicAdd(&cur[d], 1);
        csrc[rp[d] + slot] = row[e];
    }
}

// ---------------- weight prep: transpose + bf16 hi/lo split ----------------
__global__ __launch_bounds__(256) void prep_w(const float* __restrict__ lin1_w,
                                              const float* __restrict__ gcn_w,
                                              ushort_t* __restrict__ wt_hi,
                                              ushort_t* __restrict__ wt_lo) {
    int m = blockIdx.x;
    const float* W = (m == 0) ? lin1_w : gcn_w + (size_t)(m - 1) * 16384;
    ushort_t* hi = wt_hi + (size_t)m * 16384;
    ushort_t* lo = wt_lo + (size_t)m * 16384;
    for (int i = threadIdx.x; i < 16384; i += 256) {
        int k = i >> 7, n = i & 127;
        float v = W[i];
        ushort_t h = f2bf(v);
        ushort_t l = f2bf(v - bf2f(h));
        hi[n * 128 + k] = h;
        lo[n * 128 + k] = l;
    }
}

// ---------------- MFMA GEMM: out[N,128] = A[N,128] @ W, 3-term bf16 split ----------------
__global__ __launch_bounds__(256) void gemm_mfma(const float* __restrict__ A,
                                                 const ushort_t* __restrict__ wt_hi,
                                                 const ushort_t* __restrict__ wt_lo,
                                                 const float* __restrict__ bias,
                                                 float* __restrict__ out_f32,
                                                 ushort_t* __restrict__ out_bf16,
                                                 int N, int mode) {
    const int lane = threadIdx.x & 63;
    const int wid = threadIdx.x >> 6;
    const int rowBase = blockIdx.x * 128 + wid * 32;
    const int l15 = lane & 15, lg = lane >> 4;

    f32x4 acc[2][8];
#pragma unroll
    for (int rt = 0; rt < 2; ++rt)
#pragma unroll
        for (int ct = 0; ct < 8; ++ct) acc[rt][ct] = (f32x4){0.f, 0.f, 0.f, 0.f};

#pragma unroll
    for (int ks = 0; ks < 4; ++ks) {
        bf16x8 ahi[2], alo[2];
#pragma unroll
        for (int rt = 0; rt < 2; ++rt) {
            int r = rowBase + rt * 16 + l15;
            float av[8];
            if (r < N) {
                const float* ap = A + (size_t)r * 128 + ks * 32 + lg * 8;
                float4 a0 = *(const float4*)(ap);
                float4 a1 = *(const float4*)(ap + 4);
                av[0] = a0.x; av[1] = a0.y; av[2] = a0.z; av[3] = a0.w;
                av[4] = a1.x; av[5] = a1.y; av[6] = a1.z; av[7] = a1.w;
            } else {
#pragma unroll
                for (int j = 0; j < 8; ++j) av[j] = 0.f;
            }
#pragma unroll
            for (int j = 0; j < 8; ++j) {
                ushort_t h = f2bf(av[j]);
                ahi[rt][j] = (short)h;
                alo[rt][j] = (short)f2bf(av[j] - bf2f(h));
            }
        }
#pragma unroll
        for (int ct = 0; ct < 8; ++ct) {
            size_t boff = (size_t)(ct * 16 + l15) * 128 + ks * 32 + lg * 8;
            bf16x8 bhi = *(const bf16x8*)(wt_hi + boff);
            bf16x8 blo = *(const bf16x8*)(wt_lo + boff);
            acc[0][ct] = __builtin_amdgcn_mfma_f32_16x16x32_bf16(ahi[0], bhi, acc[0][ct], 0, 0, 0);
            acc[1][ct] = __builtin_amdgcn_mfma_f32_16x16x32_bf16(ahi[1], bhi, acc[1][ct], 0, 0, 0);
            acc[0][ct] = __builtin_amdgcn_mfma_f32_16x16x32_bf16(alo[0], bhi, acc[0][ct], 0, 0, 0);
            acc[1][ct] = __builtin_amdgcn_mfma_f32_16x16x32_bf16(alo[1], bhi, acc[1][ct], 0, 0, 0);
            acc[0][ct] = __builtin_amdgcn_mfma_f32_16x16x32_bf16(ahi[0], blo, acc[0][ct], 0, 0, 0);
            acc[1][ct] = __builtin_amdgcn_mfma_f32_16x16x32_bf16(ahi[1], blo, acc[1][ct], 0, 0, 0);
        }
    }

#pragma unroll
    for (int rt = 0; rt < 2; ++rt) {
#pragma unroll
        for (int reg = 0; reg < 4; ++reg) {
            int row = rowBase + rt * 16 + lg * 4 + reg;
            if (row >= N) continue;
#pragma unroll
            for (int ct = 0; ct < 8; ++ct) {
                int colc = ct * 16 + l15;
                float v = acc[rt][ct][reg];
                if (mode == 0) {
                    v += bias[colc];
                    v = v > 0.f ? v : expf(v) - 1.f;
                    out_f32[(size_t)row * 128 + colc] = v;
                } else {
                    out_bf16[(size_t)row * 128 + colc] = f2bf(v);
                }
            }
        }
    }
}

// ---------------- gather-aggregate: 16 lanes/node, 4-edge unroll ----------------
// block = 256 thr = 16 nodes; each lane covers 8 bf16 cols (16 B)
__global__ __launch_bounds__(256) void gather_agg(const int* __restrict__ rp,
                                                  const int* __restrict__ csrc,
                                                  const float* __restrict__ dinv,
                                                  const ushort_t* __restrict__ hwb,
                                                  const float* __restrict__ bias,
                                                  float* __restrict__ h) {
    int v = blockIdx.x * 16 + (threadIdx.x >> 4);
    if (v >= NN) return;
    int c8 = (threadIdx.x & 15) << 3;          // bf16 column offset
    float di = dinv[v];
    int s = rp[v], e = rp[v + 1];
    float acc[8] = {};

    int i = s;
    for (; i + 4 <= e; i += 4) {
        int u0 = csrc[i], u1 = csrc[i + 1], u2 = csrc[i + 2], u3 = csrc[i + 3];
        float w0 = dinv[u0] * di, w1 = dinv[u1] * di, w2 = dinv[u2] * di, w3 = dinv[u3] * di;
        ushort8_t r0 = *(const ushort8_t*)(hwb + (size_t)u0 * 128 + c8);
        ushort8_t r1 = *(const ushort8_t*)(hwb + (size_t)u1 * 128 + c8);
        ushort8_t r2 = *(const ushort8_t*)(hwb + (size_t)u2 * 128 + c8);
        ushort8_t r3 = *(const ushort8_t*)(hwb + (size_t)u3 * 128 + c8);
#pragma unroll
        for (int j = 0; j < 8; ++j) {
            acc[j] = fmaf(w0, bf2f(r0[j]), acc[j]);
            acc[j] = fmaf(w1, bf2f(r1[j]), acc[j]);
            acc[j] = fmaf(w2, bf2f(r2[j]), acc[j]);
            acc[j] = fmaf(w3, bf2f(r3[j]), acc[j]);
        }
    }
    for (; i < e; ++i) {
        int u = csrc[i];
        float w = dinv[u] * di;
        ushort8_t r0 = *(const ushort8_t*)(hwb + (size_t)u * 128 + c8);
#pragma unroll
        for (int j = 0; j < 8; ++j) acc[j] = fmaf(w, bf2f(r0[j]), acc[j]);
    }

    // self-loop + bias + ELU
    ushort8_t sv = *(const ushort8_t*)(hwb + (size_t)v * 128 + c8);
    float w2s = di * di;
    float o[8];
#pragma unroll
    for (int j = 0; j < 8; ++j) {
        float t = acc[j] + w2s * bf2f(sv[j]) + bias[c8 + j];
        o[j] = t > 0.f ? t : expf(t) - 1.f;
    }
    float4* hp = (float4*)(h + (size_t)v * 128 + c8);
    hp[0] = make_float4(o[0], o[1], o[2], o[3]);
    hp[1] = make_float4(o[4], o[5], o[6], o[7]);
}

// ---------------- readout: reps[g] += mean over nodes of graph g ----------------
__global__ __launch_bounds__(256) void readout(const float* __restrict__ h,
                                               const int* __restrict__ batch,
                                               int n, float* __restrict__ reps) {
    int g = blockIdx.x;
    int lo = 0, hi = n;
    while (lo < hi) { int m = (lo + hi) >> 1; if (batch[m] < g) lo = m + 1; else hi = m; }
    int s = lo;
    lo = 0; hi = n;
    while (lo < hi) { int m = (lo + hi) >> 1; if (batch[m] < g + 1) lo = m + 1; else hi = m; }
    int e = lo;
    __shared__ float part[8][128];
    int rid = threadIdx.x >> 5;
    int c4 = (threadIdx.x & 31) << 2;
    float4 acc = make_float4(0.f, 0.f, 0.f, 0.f);
    for (int v = s + rid; v < e; v += 8) {
        float4 t = *(const float4*)(h + (size_t)v * 128 + c4);
        acc.x += t.x; acc.y += t.y; acc.z += t.z; acc.w += t.w;
    }
    *(float4*)(&part[rid][c4]) = acc;
    __syncthreads();
    if (rid == 0) {
        float sx = 0.f, sy = 0.f, sz = 0.f, sw = 0.f;
#pragma unroll
        for (int r = 0; r < 8; ++r) {
            float4 a = *(const float4*)(&part[r][c4]);
            sx += a.x; sy += a.y; sz += a.z; sw += a.w;
        }
        float cnt = (float)(e - s > 0 ? e - s : 1);
        float inv = 1.f / cnt;
        float* rp_ = reps + (size_t)g * 128 + c4;
        rp_[0] += sx * inv;
        rp_[1] += sy * inv;
        rp_[2] += sz * inv;
        rp_[3] += sw * inv;
    }
}

// ---------------- head GEMM (fp32 VALU, tiny) ----------------
__global__ __launch_bounds__(256) void gemm128(const float* __restrict__ A,
                                               const float* __restrict__ W,
                                               const float* __restrict__ bias,
                                               float* __restrict__ out,
                                               int N, int applyElu) {
    __shared__ float xs[64][128];
    __shared__ float ws[128][64];
    const int tid = threadIdx.x;
    const int rowBase = blockIdx.x * 64;
    const int colBase = blockIdx.y * 64;
#pragma unroll
    for (int it = 0; it < 8; ++it) {
        int idx = it * 256 + tid;
        int r = idx >> 5;
        int c4 = (idx & 31) << 2;
        int gr = rowBase + r;
        float4 v = make_float4(0.f, 0.f, 0.f, 0.f);
        if (gr < N) v = *(const float4*)(A + (size_t)gr * 128 + c4);
        *(float4*)(&xs[r][c4]) = v;
    }
#pragma unroll
    for (int it = 0; it < 8; ++it) {
        int idx = it * 256 + tid;
        int k = idx >> 4;
        int c4 = (idx & 15) << 2;
        *(float4*)(&ws[k][c4]) = *(const float4*)(W + (size_t)k * 128 + colBase + c4);
    }
    __syncthreads();
    const int rowg = tid >> 4, colg = tid & 15;
    const int r0 = rowg * 4, c0 = colg * 4;
    float acc[4][4] = {};
#pragma unroll 2
    for (int kb = 0; kb < 128; kb += 4) {
        float4 xr[4], wr[4];
#pragma unroll
        for (int i = 0; i < 4; ++i) xr[i] = *(const float4*)(&xs[r0 + i][kb]);
#pragma unroll
        for (int kk = 0; kk < 4; ++kk) wr[kk] = *(const float4*)(&ws[kb + kk][c0]);
#pragma unroll
        for (int i = 0; i < 4; ++i) {
            const float* xp = (const float*)&xr[i];
#pragma unroll
            for (int kk = 0; kk < 4; ++kk) {
                float xv = xp[kk];
                acc[i][0] = fmaf(xv, wr[kk].x, acc[i][0]);
                acc[i][1] = fmaf(xv, wr[kk].y, acc[i][1]);
                acc[i][2] = fmaf(xv, wr[kk].z, acc[i][2]);
                acc[i][3] = fmaf(xv, wr[kk].w, acc[i][3]);
            }
        }
    }
    float4 b4 = make_float4(0.f, 0.f, 0.f, 0.f);
    if (bias) b4 = *(const float4*)(bias + colBase + c0);
#pragma unroll
    for (int i = 0; i < 4; ++i) {
        int gr = rowBase + r0 + i;
        if (gr < N) {
            float4 o;
            o.x = acc[i][0] + b4.x;
            o.y = acc[i][1] + b4.y;
            o.z = acc[i][2] + b4.z;
            o.w = acc[i][3] + b4.w;
            if (applyElu) {
                o.x = o.x > 0.f ? o.x : expf(o.x) - 1.f;
                o.y = o.y > 0.f ? o.y : expf(o.y) - 1.f;
                o.z = o.z > 0.f ? o.z : expf(o.z) - 1.f;
                o.w = o.w > 0.f ? o.w : expf(o.w) - 1.f;
            }
            *(float4*)(out + (size_t)gr * 128 + colBase + c0) = o;
        }
    }
}

// ---------------- classifier + log_softmax ----------------
__global__ __launch_bounds__(64) void cls_logsoftmax(const float* __restrict__ g,
                                                     const float* __restrict__ cw,
                                                     const float* __restrict__ cb,
                                                     float* __restrict__ out) {
    int r = blockIdx.x;
    __shared__ float row[128];
    __shared__ float lg[10];
    int t = threadIdx.x;
    row[t] = g[(size_t)r * 128 + t];
    row[64 + t] = g[(size_t)r * 128 + 64 + t];
    __syncthreads();
    if (t < 10) {
        float a = cb[t];
        for (int k = 0; k < 128; ++k) a = fmaf(row[k], cw[k * 10 + t], a);
        lg[t] = a;
    }
    __syncthreads();
    if (t == 0) {
        float m = lg[0];
#pragma unroll
        for (int j = 1; j < 10; ++j) m = fmaxf(m, lg[j]);
        float se = 0.f;
#pragma unroll
        for (int j = 0; j < 10; ++j) se += expf(lg[j] - m);
        float L = logf(se);
#pragma unroll
        for (int j = 0; j < 10; ++j) out[(size_t)r * 10 + j] = lg[j] - m - L;
    }
}

extern "C" void kernel_launch(void* const* d_in, const int* in_sizes, int n_in,
                              void* d_out, int out_size, void* d_ws, size_t ws_size,
                              hipStream_t stream) {
    const float* x        = (const float*)d_in[0];
    const float* lin1_w   = (const float*)d_in[1];
    const float* lin1_b   = (const float*)d_in[2];
    const float* gcn_w    = (const float*)d_in[3];
    const float* gcn_b    = (const float*)d_in[4];
    const float* lin_out_w= (const float*)d_in[5];
    const float* lin_out_b= (const float*)d_in[6];
    const float* cls_w    = (const float*)d_in[7];
    const float* cls_b    = (const float*)d_in[8];
    const int*   ei       = (const int*)d_in[9];
    const int*   batch    = (const int*)d_in[10];
    float* out = (float*)d_out;

    const int* erow = ei;
    const int* ecol = ei + NE;
    const int NB_SCAN = (NN + 1023) / 1024;

    float*    h     = (float*)d_ws;                        // NN*128 f32
    ushort_t* hwb   = (ushort_t*)(h + (size_t)NN * 128);   // NN*128 bf16
    float*    dinv  = (float*)(hwb + (size_t)NN * 128);    // NN
    float*    reps  = dinv + NN;                           // NG*128
    float*    gbuf  = reps + (size_t)NG * 128;             // NG*128
    int*      cnt   = (int*)(gbuf + (size_t)NG * 128);     // NN
    int*      rp    = cnt + NN;                            // NN+1
    int*      cur   = rp + NN + 1;                         // NN
    int*      bsum  = cur + NN;                            // NB_SCAN+1
    int*      csrc  = bsum + NB_SCAN + 1;                  // NE
    ushort_t* wt_hi = (ushort_t*)(csrc + NE);              // 4*16384
    ushort_t* wt_lo = wt_hi + 4 * 16384;                   // 4*16384

    hipMemsetAsync(cnt, 0, NN * sizeof(int), stream);
    hipMemsetAsync(cur, 0, NN * sizeof(int), stream);
    hipMemsetAsync(reps, 0, (size_t)NG * 128 * sizeof(float), stream);

    deg_hist<<<(NE + 255) / 256, 256, 0, stream>>>(ecol, cnt, NE);
    make_dinv<<<(NN + 255) / 256, 256, 0, stream>>>(cnt, dinv, NN);
    scan_local<<<NB_SCAN, 256, 0, stream>>>(cnt, rp, bsum, NN);
    scan_blocks<<<1, 128, 0, stream>>>(bsum, NB_SCAN);
    scan_add<<<(NN + 255) / 256, 256, 0, stream>>>(rp, bsum, NN, NB_SCAN);
    fill_csr<<<(NE + 255) / 256, 256, 0, stream>>>(erow, ecol, rp, cur, csrc, NE);
    prep_w<<<4, 256, 0, stream>>>(lin1_w, gcn_w, wt_hi, wt_lo);

    const int GEMM_GRID = (NN + 127) / 128;

    gemm_mfma<<<GEMM_GRID, 256, 0, stream>>>(x, wt_hi, wt_lo, lin1_b, h, nullptr, NN, 0);
    readout<<<NG, 256, 0, stream>>>(h, batch, NN, reps);

    for (int i = 0; i < 3; ++i) {
        gemm_mfma<<<GEMM_GRID, 256, 0, stream>>>(h, wt_hi + (size_t)(i + 1) * 16384,
                                                 wt_lo + (size_t)(i + 1) * 16384,
                                                 nullptr, nullptr, hwb, NN, 1);
        gather_agg<<<(NN + 15) / 16, 256, 0, stream>>>(rp, csrc, dinv, hwb, gcn_b + (size_t)i * 128, h);
        readout<<<NG, 256, 0, stream>>>(h, batch, NN, reps);
    }

    dim3 gs((NG + 63) / 64, 2);
    gemm128<<<gs, 256, 0, stream>>>(reps, lin_out_w, lin_out_b, gbuf, NG, 1);
    cls_logsoftmax<<<NG, 64, 0, stream>>>(gbuf, cls_w, cls_b, out);
}

// Round 5
// 588.123 us; speedup vs baseline: 14.8934x; 1.1906x over previous
//
#include <hip/hip_runtime.h>
#include <hip/hip_bf16.h>
#include <math.h>

#define NN 100000
#define NE 1600000
#define HID 128
#define NG 512
#define NB 512          // dst buckets
#define RB 196          // nodes per bucket (512*196 = 100352 >= NN)

typedef unsigned short ushort_t;
typedef __attribute__((ext_vector_type(8))) short bf16x8;
typedef __attribute__((ext_vector_type(8))) unsigned short ushort8_t;
typedef __attribute__((ext_vector_type(4))) float f32x4;

__device__ __forceinline__ ushort_t f2bf(float v) {
    unsigned u = __float_as_uint(v);
    unsigned r = (u + 0x7FFF + ((u >> 16) & 1)) >> 16;
    return (ushort_t)r;
}
__device__ __forceinline__ float bf2f(ushort_t u) {
    return __uint_as_float((unsigned)u << 16);
}

// ---------------- bucket histogram ----------------
__global__ __launch_bounds__(256) void bucket_hist(const int* __restrict__ ecol, int* __restrict__ ghist, int E) {
    __shared__ int lh[NB];
    for (int i = threadIdx.x; i < NB; i += 256) lh[i] = 0;
    __syncthreads();
    for (int e = blockIdx.x * 256 + threadIdx.x; e < E; e += gridDim.x * 256)
        atomicAdd(&lh[ecol[e] / RB], 1);
    __syncthreads();
    for (int i = threadIdx.x; i < NB; i += 256) {
        int c = lh[i];
        if (c) atomicAdd(&ghist[i], c);
    }
}

// ---------------- scan buckets (1 block, NB threads) ----------------
__global__ __launch_bounds__(NB) void bucket_scan(const int* __restrict__ ghist, int* __restrict__ brp,
                                                  int* __restrict__ gcur, int* __restrict__ rp) {
    __shared__ int s[NB];
    int t = threadIdx.x;
    int v = ghist[t];
    s[t] = v;
    __syncthreads();
    for (int off = 1; off < NB; off <<= 1) {
        int x = (t >= off) ? s[t - off] : 0;
        __syncthreads();
        s[t] += x;
        __syncthreads();
    }
    int ex = s[t] - v;
    brp[t] = ex;
    gcur[t] = ex;
    if (t == NB - 1) { brp[NB] = s[t]; rp[NN] = s[t]; }
}

// ---------------- partition edges into bucket-contiguous (src,dst) pairs ----------------
#define CHUNK 4096
__global__ __launch_bounds__(256) void partition_edges(const int* __restrict__ erow, const int* __restrict__ ecol,
                                                       int* __restrict__ gcur, int2* __restrict__ pairs, int E) {
    __shared__ int cnt[NB];
    __shared__ int base[NB];
    const int t = threadIdx.x;
    const int e0 = blockIdx.x * CHUNK;
    const int e1 = min(e0 + CHUNK, E);
    for (int i = t; i < NB; i += 256) cnt[i] = 0;
    __syncthreads();
    for (int e = e0 + t; e < e1; e += 256) atomicAdd(&cnt[ecol[e] / RB], 1);
    __syncthreads();
    for (int i = t; i < NB; i += 256) {
        int c = cnt[i];
        base[i] = c ? atomicAdd(&gcur[i], c) : 0;
        cnt[i] = 0;
    }
    __syncthreads();
    for (int e = e0 + t; e < e1; e += 256) {
        int d = ecol[e];
        int b = d / RB;
        int off = atomicAdd(&cnt[b], 1);
        pairs[base[b] + off] = make_int2(erow[e], d);
    }
}

// ---------------- per-bucket: degrees, dinv, rp, fill csrc ----------------
__global__ __launch_bounds__(256) void bucket_fill(const int2* __restrict__ pairs, const int* __restrict__ brp,
                                                   int* __restrict__ rp, float* __restrict__ dinv,
                                                   int* __restrict__ csrc) {
    __shared__ int cnt[RB];
    __shared__ int cur[RB];
    __shared__ int sc[256];
    const int b = blockIdx.x, t = threadIdx.x;
    const int nbase = b * RB;
    const int s = brp[b], e = brp[b + 1];
    for (int i = t; i < RB; i += 256) cnt[i] = 0;
    __syncthreads();
    for (int i = s + t; i < e; i += 256) atomicAdd(&cnt[pairs[i].y - nbase], 1);
    __syncthreads();
    int v = (t < RB) ? cnt[t] : 0;
    sc[t] = v;
    __syncthreads();
    for (int off = 1; off < 256; off <<= 1) {
        int x = (t >= off) ? sc[t - off] : 0;
        __syncthreads();
        sc[t] += x;
        __syncthreads();
    }
    if (t < RB) {
        int ex = s + sc[t] - v;
        int node = nbase + t;
        if (node < NN) {
            rp[node] = ex;
            dinv[node] = rsqrtf((float)v + 1.0f);
        }
        cur[t] = ex;
    }
    __syncthreads();
    for (int i = s + t; i < e; i += 256) {
        int2 p = pairs[i];
        int slot = atomicAdd(&cur[p.y - nbase], 1);
        csrc[slot] = p.x;
    }
}

// ---------------- weight prep: transpose + bf16 hi/lo split ----------------
__global__ __launch_bounds__(256) void prep_w(const float* __restrict__ lin1_w,
                                              const float* __restrict__ gcn_w,
                                              ushort_t* __restrict__ wt_hi,
                                              ushort_t* __restrict__ wt_lo) {
    int m = blockIdx.x >> 3;             // matrix 0..3
    int chunk = blockIdx.x & 7;          // 1/8 of 16384
    const float* W = (m == 0) ? lin1_w : gcn_w + (size_t)(m - 1) * 16384;
    ushort_t* hi = wt_hi + (size_t)m * 16384;
    ushort_t* lo = wt_lo + (size_t)m * 16384;
    for (int i = chunk * 2048 + threadIdx.x; i < (chunk + 1) * 2048; i += 256) {
        int k = i >> 7, n = i & 127;
        float v = W[i];
        ushort_t h = f2bf(v);
        ushort_t l = f2bf(v - bf2f(h));
        hi[n * 128 + k] = h;
        lo[n * 128 + k] = l;
    }
}

// ---------------- MFMA GEMM, 3-term bf16 split ----------------
// mode 0: out_f32 = elu(acc + bias); mode 1: out_bf16 = bf16(dinv[row] * acc)
__global__ __launch_bounds__(256) void gemm_mfma(const float* __restrict__ A,
                                                 const ushort_t* __restrict__ wt_hi,
                                                 const ushort_t* __restrict__ wt_lo,
                                                 const float* __restrict__ bias,
                                                 const float* __restrict__ dinv,
                                                 float* __restrict__ out_f32,
                                                 ushort_t* __restrict__ out_bf16,
                                                 int N, int mode) {
    const int lane = threadIdx.x & 63;
    const int wid = threadIdx.x >> 6;
    const int rowBase = blockIdx.x * 128 + wid * 32;
    const int l15 = lane & 15, lg = lane >> 4;

    f32x4 acc[2][8];
#pragma unroll
    for (int rt = 0; rt < 2; ++rt)
#pragma unroll
        for (int ct = 0; ct < 8; ++ct) acc[rt][ct] = (f32x4){0.f, 0.f, 0.f, 0.f};

#pragma unroll
    for (int ks = 0; ks < 4; ++ks) {
        bf16x8 ahi[2], alo[2];
#pragma unroll
        for (int rt = 0; rt < 2; ++rt) {
            int r = rowBase + rt * 16 + l15;
            float av[8];
            if (r < N) {
                const float* ap = A + (size_t)r * 128 + ks * 32 + lg * 8;
                float4 a0 = *(const float4*)(ap);
                float4 a1 = *(const float4*)(ap + 4);
                av[0] = a0.x; av[1] = a0.y; av[2] = a0.z; av[3] = a0.w;
                av[4] = a1.x; av[5] = a1.y; av[6] = a1.z; av[7] = a1.w;
            } else {
#pragma unroll
                for (int j = 0; j < 8; ++j) av[j] = 0.f;
            }
#pragma unroll
            for (int j = 0; j < 8; ++j) {
                ushort_t h = f2bf(av[j]);
                ahi[rt][j] = (short)h;
                alo[rt][j] = (short)f2bf(av[j] - bf2f(h));
            }
        }
#pragma unroll
        for (int ct = 0; ct < 8; ++ct) {
            size_t boff = (size_t)(ct * 16 + l15) * 128 + ks * 32 + lg * 8;
            bf16x8 bhi = *(const bf16x8*)(wt_hi + boff);
            bf16x8 blo = *(const bf16x8*)(wt_lo + boff);
            acc[0][ct] = __builtin_amdgcn_mfma_f32_16x16x32_bf16(ahi[0], bhi, acc[0][ct], 0, 0, 0);
            acc[1][ct] = __builtin_amdgcn_mfma_f32_16x16x32_bf16(ahi[1], bhi, acc[1][ct], 0, 0, 0);
            acc[0][ct] = __builtin_amdgcn_mfma_f32_16x16x32_bf16(alo[0], bhi, acc[0][ct], 0, 0, 0);
            acc[1][ct] = __builtin_amdgcn_mfma_f32_16x16x32_bf16(alo[1], bhi, acc[1][ct], 0, 0, 0);
            acc[0][ct] = __builtin_amdgcn_mfma_f32_16x16x32_bf16(ahi[0], blo, acc[0][ct], 0, 0, 0);
            acc[1][ct] = __builtin_amdgcn_mfma_f32_16x16x32_bf16(ahi[1], blo, acc[1][ct], 0, 0, 0);
        }
    }

#pragma unroll
    for (int rt = 0; rt < 2; ++rt) {
#pragma unroll
        for (int reg = 0; reg < 4; ++reg) {
            int row = rowBase + rt * 16 + lg * 4 + reg;
            if (row >= N) continue;
            if (mode == 0) {
#pragma unroll
                for (int ct = 0; ct < 8; ++ct) {
                    int colc = ct * 16 + l15;
                    float v = acc[rt][ct][reg] + bias[colc];
                    v = v > 0.f ? v : expf(v) - 1.f;
                    out_f32[(size_t)row * 128 + colc] = v;
                }
            } else {
                float dv = dinv[row];
#pragma unroll
                for (int ct = 0; ct < 8; ++ct) {
                    int colc = ct * 16 + l15;
                    out_bf16[(size_t)row * 128 + colc] = f2bf(acc[rt][ct][reg] * dv);
                }
            }
        }
    }
}

// ---------------- gather: h[v] = elu(dinv[v]*(sum hwb[u] + hwb[v]) + bias) ----------------
// hwb rows are pre-scaled by dinv[u]; 16 lanes/node, 8-edge unroll
__global__ __launch_bounds__(256) void gather_agg(const int* __restrict__ rp,
                                                  const int* __restrict__ csrc,
                                                  const float* __restrict__ dinv,
                                                  const ushort_t* __restrict__ hwb,
                                                  const float* __restrict__ bias,
                                                  float* __restrict__ h) {
    int v = blockIdx.x * 16 + (threadIdx.x >> 4);
    if (v >= NN) return;
    int c8 = (threadIdx.x & 15) << 3;
    int s = rp[v], e = rp[v + 1];
    float acc[8] = {};

    int i = s;
    for (; i + 8 <= e; i += 8) {
        int u[8];
#pragma unroll
        for (int k = 0; k < 8; ++k) u[k] = csrc[i + k];
        ushort8_t r[8];
#pragma unroll
        for (int k = 0; k < 8; ++k) r[k] = *(const ushort8_t*)(hwb + (size_t)u[k] * 128 + c8);
#pragma unroll
        for (int k = 0; k < 8; ++k)
#pragma unroll
            for (int j = 0; j < 8; ++j) acc[j] += bf2f(r[k][j]);
    }
    for (; i < e; ++i) {
        int u = csrc[i];
        ushort8_t r0 = *(const ushort8_t*)(hwb + (size_t)u * 128 + c8);
#pragma unroll
        for (int j = 0; j < 8; ++j) acc[j] += bf2f(r0[j]);
    }

    float di = dinv[v];
    ushort8_t sv = *(const ushort8_t*)(hwb + (size_t)v * 128 + c8);
    float o[8];
#pragma unroll
    for (int j = 0; j < 8; ++j) {
        float t = di * (acc[j] + bf2f(sv[j])) + bias[c8 + j];
        o[j] = t > 0.f ? t : expf(t) - 1.f;
    }
    float4* hp = (float4*)(h + (size_t)v * 128 + c8);
    hp[0] = make_float4(o[0], o[1], o[2], o[3]);
    hp[1] = make_float4(o[4], o[5], o[6], o[7]);
}

// ---------------- readout: 4 blocks per graph, atomic accumulate ----------------
__global__ __launch_bounds__(128) void readout(const float* __restrict__ h,
                                               const int* __restrict__ batch,
                                               int n, float* __restrict__ reps) {
    int g = blockIdx.x >> 2;
    int part = blockIdx.x & 3;
    int lo = 0, hi = n;
    while (lo < hi) { int m = (lo + hi) >> 1; if (batch[m] < g) lo = m + 1; else hi = m; }
    int s = lo;
    lo = 0; hi = n;
    while (lo < hi) { int m = (lo + hi) >> 1; if (batch[m] < g + 1) lo = m + 1; else hi = m; }
    int e = lo;
    int c = threadIdx.x;
    float acc = 0.f;
    for (int v = s + part; v < e; v += 4) acc += h[(size_t)v * 128 + c];
    float cnt = (float)(e - s > 0 ? e - s : 1);
    unsafeAtomicAdd(&reps[(size_t)g * 128 + c], acc / cnt);
}

// ---------------- head GEMM (fp32 VALU, tiny) ----------------
__global__ __launch_bounds__(256) void gemm128(const float* __restrict__ A,
                                               const float* __restrict__ W,
                                               const float* __restrict__ bias,
                                               float* __restrict__ out,
                                               int N, int applyElu) {
    __shared__ float xs[64][128];
    __shared__ float ws[128][64];
    const int tid = threadIdx.x;
    const int rowBase = blockIdx.x * 64;
    const int colBase = blockIdx.y * 64;
#pragma unroll
    for (int it = 0; it < 8; ++it) {
        int idx = it * 256 + tid;
        int r = idx >> 5;
        int c4 = (idx & 31) << 2;
        int gr = rowBase + r;
        float4 v = make_float4(0.f, 0.f, 0.f, 0.f);
        if (gr < N) v = *(const float4*)(A + (size_t)gr * 128 + c4);
        *(float4*)(&xs[r][c4]) = v;
    }
#pragma unroll
    for (int it = 0; it < 8; ++it) {
        int idx = it * 256 + tid;
        int k = idx >> 4;
        int c4 = (idx & 15) << 2;
        *(float4*)(&ws[k][c4]) = *(const float4*)(W + (size_t)k * 128 + colBase + c4);
    }
    __syncthreads();
    const int rowg = tid >> 4, colg = tid & 15;
    const int r0 = rowg * 4, c0 = colg * 4;
    float acc[4][4] = {};
#pragma unroll 2
    for (int kb = 0; kb < 128; kb += 4) {
        float4 xr[4], wr[4];
#pragma unroll
        for (int i = 0; i < 4; ++i) xr[i] = *(const float4*)(&xs[r0 + i][kb]);
#pragma unroll
        for (int kk = 0; kk < 4; ++kk) wr[kk] = *(const float4*)(&ws[kb + kk][c0]);
#pragma unroll
        for (int i = 0; i < 4; ++i) {
            const float* xp = (const float*)&xr[i];
#pragma unroll
            for (int kk = 0; kk < 4; ++kk) {
                float xv = xp[kk];
                acc[i][0] = fmaf(xv, wr[kk].x, acc[i][0]);
                acc[i][1] = fmaf(xv, wr[kk].y, acc[i][1]);
                acc[i][2] = fmaf(xv, wr[kk].z, acc[i][2]);
                acc[i][3] = fmaf(xv, wr[kk].w, acc[i][3]);
            }
        }
    }
    float4 b4 = make_float4(0.f, 0.f, 0.f, 0.f);
    if (bias) b4 = *(const float4*)(bias + colBase + c0);
#pragma unroll
    for (int i = 0; i < 4; ++i) {
        int gr = rowBase + r0 + i;
        if (gr < N) {
            float4 o;
            o.x = acc[i][0] + b4.x;
            o.y = acc[i][1] + b4.y;
            o.z = acc[i][2] + b4.z;
            o.w = acc[i][3] + b4.w;
            if (applyElu) {
                o.x = o.x > 0.f ? o.x : expf(o.x) - 1.f;
                o.y = o.y > 0.f ? o.y : expf(o.y) - 1.f;
                o.z = o.z > 0.f ? o.z : expf(o.z) - 1.f;
                o.w = o.w > 0.f ? o.w : expf(o.w) - 1.f;
            }
            *(float4*)(out + (size_t)gr * 128 + colBase + c0) = o;
        }
    }
}

// ---------------- classifier + log_softmax ----------------
__global__ __launch_bounds__(64) void cls_logsoftmax(const float* __restrict__ g,
                                                     const float* __restrict__ cw,
                                                     const float* __restrict__ cb,
                                                     float* __restrict__ out) {
    int r = blockIdx.x;
    __shared__ float row[128];
    __shared__ float lg[10];
    int t = threadIdx.x;
    row[t] = g[(size_t)r * 128 + t];
    row[64 + t] = g[(size_t)r * 128 + 64 + t];
    __syncthreads();
    if (t < 10) {
        float a = cb[t];
        for (int k = 0; k < 128; ++k) a = fmaf(row[k], cw[k * 10 + t], a);
        lg[t] = a;
    }
    __syncthreads();
    if (t == 0) {
        float m = lg[0];
#pragma unroll
        for (int j = 1; j < 10; ++j) m = fmaxf(m, lg[j]);
        float se = 0.f;
#pragma unroll
        for (int j = 0; j < 10; ++j) se += expf(lg[j] - m);
        float L = logf(se);
#pragma unroll
        for (int j = 0; j < 10; ++j) out[(size_t)r * 10 + j] = lg[j] - m - L;
    }
}

extern "C" void kernel_launch(void* const* d_in, const int* in_sizes, int n_in,
                              void* d_out, int out_size, void* d_ws, size_t ws_size,
                              hipStream_t stream) {
    const float* x        = (const float*)d_in[0];
    const float* lin1_w   = (const float*)d_in[1];
    const float* lin1_b   = (const float*)d_in[2];
    const float* gcn_w    = (const float*)d_in[3];
    const float* gcn_b    = (const float*)d_in[4];
    const float* lin_out_w= (const float*)d_in[5];
    const float* lin_out_b= (const float*)d_in[6];
    const float* cls_w    = (const float*)d_in[7];
    const float* cls_b    = (const float*)d_in[8];
    const int*   ei       = (const int*)d_in[9];
    const int*   batch    = (const int*)d_in[10];
    float* out = (float*)d_out;

    const int* erow = ei;
    const int* ecol = ei + NE;

    float*    h     = (float*)d_ws;                        // NN*128 f32
    ushort_t* hwb   = (ushort_t*)(h + (size_t)NN * 128);   // NN*128 bf16
    float*    dinv  = (float*)(hwb + (size_t)NN * 128);    // NN
    float*    reps  = dinv + NN;                           // NG*128
    float*    gbuf  = reps + (size_t)NG * 128;             // NG*128
    int*      rp    = (int*)(gbuf + (size_t)NG * 128);     // NN+1
    int*      csrc  = rp + NN + 1;                         // NE
    int*      ghist = csrc + NE;                           // NB
    int*      brp   = ghist + NB;                          // NB+1
    int*      gcur  = brp + NB + 1;                        // NB
    ushort_t* wt_hi = (ushort_t*)(gcur + NB);              // 4*16384
    ushort_t* wt_lo = wt_hi + 4 * 16384;                   // 4*16384
    int2*     pairs = (int2*)h;                            // aliased: used only before first gemm writes h

    hipMemsetAsync(ghist, 0, NB * sizeof(int), stream);
    hipMemsetAsync(reps, 0, (size_t)NG * 128 * sizeof(float), stream);

    // ---- CSR build (bucketed) ----
    bucket_hist<<<512, 256, 0, stream>>>(ecol, ghist, NE);
    bucket_scan<<<1, NB, 0, stream>>>(ghist, brp, gcur, rp);
    partition_edges<<<(NE + CHUNK - 1) / CHUNK, 256, 0, stream>>>(erow, ecol, gcur, pairs, NE);
    bucket_fill<<<NB, 256, 0, stream>>>(pairs, brp, rp, dinv, csrc);
    prep_w<<<32, 256, 0, stream>>>(lin1_w, gcn_w, wt_hi, wt_lo);

    const int GEMM_GRID = (NN + 127) / 128;

    // h = elu(x @ lin1_w + b)   (overwrites pairs alias — CSR build already done)
    gemm_mfma<<<GEMM_GRID, 256, 0, stream>>>(x, wt_hi, wt_lo, lin1_b, dinv, h, nullptr, NN, 0);
    readout<<<NG * 4, 128, 0, stream>>>(h, batch, NN, reps);

    for (int i = 0; i < 3; ++i) {
        gemm_mfma<<<GEMM_GRID, 256, 0, stream>>>(h, wt_hi + (size_t)(i + 1) * 16384,
                                                 wt_lo + (size_t)(i + 1) * 16384,
                                                 nullptr, dinv, nullptr, hwb, NN, 1);
        gather_agg<<<(NN + 15) / 16, 256, 0, stream>>>(rp, csrc, dinv, hwb, gcn_b + (size_t)i * 128, h);
        readout<<<NG * 4, 128, 0, stream>>>(h, batch, NN, reps);
    }

    dim3 gs((NG + 63) / 64, 2);
    gemm128<<<gs, 256, 0, stream>>>(reps, lin_out_w, lin_out_b, gbuf, NG, 1);
    cls_logsoftmax<<<NG, 64, 0, stream>>>(gbuf, cls_w, cls_b, out);
}